// Round 1
// baseline (10249.905 us; speedup 1.0000x reference)
//
#include <hip/hip_runtime.h>
#include <cstddef>

#define N 384
#define NELEM (N*N)        // 147456
#define NCH 128
#define NMAT 256
#define EPS 1e-5f
#define TS 64
#define KT 16

// Muon quintic coefficients
#define QA 3.4445f
#define QB (-4.7750f)
#define QC 2.0315f

__device__ __forceinline__ float wave_sum(float v){
#pragma unroll
  for(int o=32;o>0;o>>=1) v += __shfl_down(v,o,64);
  return v;
}

__device__ __forceinline__ const float* mat_src(const float* ir, const float* vi, int m){
  return (m < NCH) ? (ir + (size_t)m*NELEM) : (vi + (size_t)(m-NCH)*NELEM);
}

// Frobenius norm of (M + eps) per matrix -> f[chunk-local]
__global__ __launch_bounds__(256)
void k_frob(const float* __restrict__ ir, const float* __restrict__ vi,
            float* __restrict__ f, int m0){
  int m = m0 + blockIdx.x;
  const float* src = mat_src(ir, vi, m);
  float s = 0.f;
  for(int i=threadIdx.x;i<NELEM;i+=256){ float v = src[i]+EPS; s += v*v; }
  __shared__ float sm[4];
  int lane = threadIdx.x & 63, w = threadIdx.x >> 6;
  s = wave_sum(s);
  if(lane==0) sm[w]=s;
  __syncthreads();
  if(threadIdx.x==0) f[blockIdx.x] = sqrtf(sm[0]+sm[1]+sm[2]+sm[3]);
}

// X = (M + eps) / f  (float4)
__global__ __launch_bounds__(256)
void k_init(const float* __restrict__ ir, const float* __restrict__ vi,
            const float* __restrict__ f, float* __restrict__ Xg, int m0){
  int mloc = blockIdx.z;
  const float4* src = (const float4*)mat_src(ir, vi, m0+mloc);
  float inv = 1.f / f[mloc];
  float4* X = (float4*)(Xg + (size_t)mloc*NELEM);
  int i = blockIdx.x*256 + threadIdx.x;
  float4 v = src[i];
  float4 o; o.x=(v.x+EPS)*inv; o.y=(v.y+EPS)*inv; o.z=(v.z+EPS)*inv; o.w=(v.w+EPS)*inv;
  X[i] = o;
}

// A = X * X^T  (batched NT gemm), 64x64 tile, 4x4 per thread
__global__ __launch_bounds__(256)
void k_xxt(const float* __restrict__ Xg, float* __restrict__ Ag){
  int mloc = blockIdx.z;
  const float* X = Xg + (size_t)mloc*NELEM;
  float* A = Ag + (size_t)mloc*NELEM;
  __shared__ __align__(16) float As[KT][TS+4];
  __shared__ __align__(16) float Bs[KT][TS+4];
  int tid = threadIdx.x;
  int tx = tid & 15, ty = tid >> 4;
  int i0 = blockIdx.y*TS, j0 = blockIdx.x*TS;
  int lr = tid >> 2;          // 0..63 row within tile
  int lk = (tid & 3) * 4;     // 0,4,8,12
  float acc[4][4] = {};
  for(int k0=0;k0<N;k0+=KT){
    float4 a = *(const float4*)&X[(size_t)(i0+lr)*N + k0 + lk];
    float4 b = *(const float4*)&X[(size_t)(j0+lr)*N + k0 + lk];
    As[lk+0][lr]=a.x; As[lk+1][lr]=a.y; As[lk+2][lr]=a.z; As[lk+3][lr]=a.w;
    Bs[lk+0][lr]=b.x; Bs[lk+1][lr]=b.y; Bs[lk+2][lr]=b.z; Bs[lk+3][lr]=b.w;
    __syncthreads();
#pragma unroll
    for(int k=0;k<KT;k++){
      float4 av = *(const float4*)&As[k][ty*4];
      float4 bv = *(const float4*)&Bs[k][tx*4];
      acc[0][0]+=av.x*bv.x; acc[0][1]+=av.x*bv.y; acc[0][2]+=av.x*bv.z; acc[0][3]+=av.x*bv.w;
      acc[1][0]+=av.y*bv.x; acc[1][1]+=av.y*bv.y; acc[1][2]+=av.y*bv.z; acc[1][3]+=av.y*bv.w;
      acc[2][0]+=av.z*bv.x; acc[2][1]+=av.z*bv.y; acc[2][2]+=av.z*bv.z; acc[2][3]+=av.z*bv.w;
      acc[3][0]+=av.w*bv.x; acc[3][1]+=av.w*bv.y; acc[3][2]+=av.w*bv.z; acc[3][3]+=av.w*bv.w;
    }
    __syncthreads();
  }
#pragma unroll
  for(int aa=0;aa<4;aa++){
    float4 o = make_float4(acc[aa][0],acc[aa][1],acc[aa][2],acc[aa][3]);
    *(float4*)&A[(size_t)(i0+ty*4+aa)*N + j0 + tx*4] = o;
  }
}

// C = alpha*(P*Q) + b1*D1 + b2*D2   (batched NN gemm with fused epilogue)
// D1/D2 may be null. C may alias D1 (in-place elementwise read-then-write).
__global__ __launch_bounds__(256)
void k_nn(const float* __restrict__ Pg, const float* __restrict__ Qg,
          float* Cg, const float* D1g, const float* D2g,
          float alpha, float b1, float b2){
  int mloc = blockIdx.z;
  const float* P = Pg + (size_t)mloc*NELEM;
  const float* Q = Qg + (size_t)mloc*NELEM;
  float* Cm = Cg + (size_t)mloc*NELEM;
  __shared__ __align__(16) float As[KT][TS+4];
  __shared__ __align__(16) float Bs[KT][TS+4];
  int tid = threadIdx.x;
  int tx = tid & 15, ty = tid >> 4;
  int i0 = blockIdx.y*TS, j0 = blockIdx.x*TS;
  int lr = tid >> 2;          // P-load: row 0..63
  int lk = (tid & 3) * 4;     // P-load: k 0,4,8,12
  int qr = tid >> 4;          // Q-load: row 0..15
  int qj = (tid & 15) * 4;    // Q-load: col 0..60
  float acc[4][4] = {};
  for(int k0=0;k0<N;k0+=KT){
    float4 a = *(const float4*)&P[(size_t)(i0+lr)*N + k0 + lk];
    float4 b = *(const float4*)&Q[(size_t)(k0+qr)*N + j0 + qj];
    As[lk+0][lr]=a.x; As[lk+1][lr]=a.y; As[lk+2][lr]=a.z; As[lk+3][lr]=a.w;
    *(float4*)&Bs[qr][qj] = b;
    __syncthreads();
#pragma unroll
    for(int k=0;k<KT;k++){
      float4 av = *(const float4*)&As[k][ty*4];
      float4 bv = *(const float4*)&Bs[k][tx*4];
      acc[0][0]+=av.x*bv.x; acc[0][1]+=av.x*bv.y; acc[0][2]+=av.x*bv.z; acc[0][3]+=av.x*bv.w;
      acc[1][0]+=av.y*bv.x; acc[1][1]+=av.y*bv.y; acc[1][2]+=av.y*bv.z; acc[1][3]+=av.y*bv.w;
      acc[2][0]+=av.z*bv.x; acc[2][1]+=av.z*bv.y; acc[2][2]+=av.z*bv.z; acc[2][3]+=av.z*bv.w;
      acc[3][0]+=av.w*bv.x; acc[3][1]+=av.w*bv.y; acc[3][2]+=av.w*bv.z; acc[3][3]+=av.w*bv.w;
    }
    __syncthreads();
  }
  const float* D1 = D1g ? D1g + (size_t)mloc*NELEM : nullptr;
  const float* D2 = D2g ? D2g + (size_t)mloc*NELEM : nullptr;
#pragma unroll
  for(int aa=0;aa<4;aa++){
    size_t idx = (size_t)(i0+ty*4+aa)*N + j0 + tx*4;
    float4 o = make_float4(alpha*acc[aa][0], alpha*acc[aa][1], alpha*acc[aa][2], alpha*acc[aa][3]);
    if(D1){
      float4 d = *(const float4*)&D1[idx];
      o.x += b1*d.x; o.y += b1*d.y; o.z += b1*d.z; o.w += b1*d.w;
    }
    if(D2){
      float4 d = *(const float4*)&D2[idx];
      o.x += b2*d.x; o.y += b2*d.y; o.z += b2*d.z; o.w += b2*d.w;
    }
    *(float4*)&Cm[idx] = o;
  }
}

// p[m] = sum( X .* (M+eps) )  == nuclear norm estimate
__global__ __launch_bounds__(256)
void k_trace(const float* __restrict__ Xg, const float* __restrict__ ir,
             const float* __restrict__ vi, float* __restrict__ p, int m0){
  int m = m0 + blockIdx.x;
  const float* src = mat_src(ir, vi, m);
  const float* X = Xg + (size_t)blockIdx.x*NELEM;
  float s = 0.f;
  for(int i=threadIdx.x;i<NELEM;i+=256) s += X[i]*(src[i]+EPS);
  __shared__ float sm[4];
  int lane = threadIdx.x & 63, w = threadIdx.x >> 6;
  s = wave_sum(s);
  if(lane==0) sm[w]=s;
  __syncthreads();
  if(threadIdx.x==0) p[m] = sm[0]+sm[1]+sm[2]+sm[3];
}

__global__ void k_weights(const float* __restrict__ p, float* __restrict__ w1, float* __restrict__ w2){
  int c = threadIdx.x;
  if(c < NCH){
    float a = p[c], b = p[c+NCH];
    float den = a + b + EPS;
    w1[c] = a/den;
    w2[c] = b/den;
  }
}

__global__ __launch_bounds__(256)
void k_combine(const float* __restrict__ ir, const float* __restrict__ vi,
               const float* __restrict__ w1, const float* __restrict__ w2,
               float* __restrict__ out){
  int i = blockIdx.x*256 + threadIdx.x;      // float4 index
  int c = i / (NELEM/4);                     // channel
  float4 a = ((const float4*)ir)[i];
  float4 b = ((const float4*)vi)[i];
  float x1 = w1[c], x2 = w2[c];
  float4 o;
  o.x = x1*a.x + x2*b.x; o.y = x1*a.y + x2*b.y;
  o.z = x1*a.z + x2*b.z; o.w = x1*a.w + x2*b.w;
  ((float4*)out)[i] = o;
}

extern "C" void kernel_launch(void* const* d_in, const int* in_sizes, int n_in,
                              void* d_out, int out_size, void* d_ws, size_t ws_size,
                              hipStream_t stream){
  const float* ir = (const float*)d_in[0];
  const float* vi = (const float*)d_in[1];
  float* out = (float*)d_out;
  float* ws = (float*)d_ws;

  // chunk so 3 buffers (X, A, B) + small tail fit in ws
  size_t elems = ws_size / sizeof(float);
  int CH = NMAT;
  while (CH > 1 && (size_t)3*CH*NELEM + 1024 > elems) CH >>= 1;

  float* X  = ws;
  float* A  = X + (size_t)CH*NELEM;
  float* B  = A + (size_t)CH*NELEM;
  float* p  = B + (size_t)CH*NELEM;
  float* w1 = p + NMAT;
  float* w2 = w1 + NCH;
  float* f  = w2 + NCH;

  dim3 g(N/TS, N/TS, CH);
  for(int m0=0; m0<NMAT; m0+=CH){
    k_frob<<<CH,256,0,stream>>>(ir, vi, f, m0);
    k_init<<<dim3(NELEM/4/256,1,CH),256,0,stream>>>(ir, vi, f, X, m0);
    float* Xc = X; float* Bc = B;
    // 5 quintic (Muon) iterations: X <- QA*X + QB*(XX^T)X + QC*(XX^T)^2 X
    for(int q=0;q<5;q++){
      k_xxt<<<g,256,0,stream>>>(Xc, A);
      k_nn<<<g,256,0,stream>>>(A, Xc, Bc, nullptr, nullptr, 1.f, 0.f, 0.f);   // B = A*X
      k_nn<<<g,256,0,stream>>>(A, Bc, Xc, Xc, Bc, QC, QA, QB);                // X = QC*A*B + QA*X + QB*B
    }
    // 4 cubic Newton-Schulz polish: Xnew = 1.5*X - 0.5*(XX^T)X
    for(int q=0;q<4;q++){
      k_xxt<<<g,256,0,stream>>>(Xc, A);
      k_nn<<<g,256,0,stream>>>(A, Xc, Bc, Xc, nullptr, -0.5f, 1.5f, 0.f);
      float* t = Xc; Xc = Bc; Bc = t;
    }
    k_trace<<<CH,256,0,stream>>>(Xc, ir, vi, p, m0);
  }
  k_weights<<<1,128,0,stream>>>(p, w1, w2);
  k_combine<<<(NCH*(NELEM/4))/256,256,0,stream>>>(ir, vi, w1, w2, out);
}

// Round 2
// 2454.621 us; speedup vs baseline: 4.1758x; 4.1758x over previous
//
#include <hip/hip_runtime.h>
#include <cstddef>

typedef unsigned short u16;
typedef unsigned int u32;

#define N 384
#define NELEM (N*N)        // 147456
#define NCH 128
#define NMAT 256
#define EPS 1e-5f

// Muon quintic coefficients
#define QA 3.4445f
#define QB (-4.7750f)
#define QC 2.0315f

typedef __attribute__((ext_vector_type(8))) short bf16x8;   // 8 bf16 = 4 VGPRs
typedef __attribute__((ext_vector_type(4))) float f32x4;

__device__ __forceinline__ float bf2f(u16 h){ union{u32 u; float f;} v; v.u=((u32)h)<<16; return v.f; }
__device__ __forceinline__ u16 f2bf(float x){
  union{float f;u32 u;} v; v.f=x;
  u32 r=(v.u + 0x7FFFu + ((v.u>>16)&1u))>>16;   // RNE
  return (u16)r;
}

__device__ __forceinline__ float wave_sum(float v){
#pragma unroll
  for(int o=32;o>0;o>>=1) v += __shfl_down(v,o,64);
  return v;
}

__device__ __forceinline__ const float* mat_src(const float* ir, const float* vi, int m){
  return (m < NCH) ? (ir + (size_t)m*NELEM) : (vi + (size_t)(m-NCH)*NELEM);
}

__global__ void k_zero(float* __restrict__ x, int n){
  int i = blockIdx.x*256 + threadIdx.x;
  if(i < n) x[i] = 0.f;
}

// partial Frobenius^2 of (M+eps): grid (CH, 16), atomicAdd into f[mloc]
__global__ __launch_bounds__(256)
void k_frob_part(const float* __restrict__ ir, const float* __restrict__ vi,
                 float* __restrict__ f, int m0){
  int mloc = blockIdx.x;
  const float4* s4 = (const float4*)mat_src(ir, vi, m0+mloc) + blockIdx.y*(NELEM/4/16);
  float s = 0.f;
  for(int i=threadIdx.x; i<NELEM/4/16; i+=256){
    float4 v = s4[i];
    float a=v.x+EPS, b=v.y+EPS, c=v.z+EPS, d=v.w+EPS;
    s += a*a + b*b + c*c + d*d;
  }
  __shared__ float sm[4];
  int lane=threadIdx.x&63, w=threadIdx.x>>6;
  s = wave_sum(s);
  if(lane==0) sm[w]=s;
  __syncthreads();
  if(threadIdx.x==0) atomicAdd(&f[mloc], sm[0]+sm[1]+sm[2]+sm[3]);
}

// X = bf16((M+eps) * rsqrt(f))   grid (144,1,CH)
__global__ __launch_bounds__(256)
void k_init(const float* __restrict__ ir, const float* __restrict__ vi,
            const float* __restrict__ f, u16* __restrict__ Xg, int m0){
  int mloc = blockIdx.z;
  const float4* src = (const float4*)mat_src(ir, vi, m0+mloc);
  float inv = rsqrtf(f[mloc]);
  ushort4* X4 = (ushort4*)(Xg + (size_t)mloc*NELEM);
  int i = blockIdx.x*256 + threadIdx.x;
  float4 v = src[i];
  ushort4 o;
  o.x=f2bf((v.x+EPS)*inv); o.y=f2bf((v.y+EPS)*inv);
  o.z=f2bf((v.z+EPS)*inv); o.w=f2bf((v.w+EPS)*inv);
  X4[i] = o;
}

// Y = X^T (bf16, LDS-tiled)  grid (6,6,CH)
__global__ __launch_bounds__(256)
void k_transp(const u16* __restrict__ Xg, u16* __restrict__ Yg){
  __shared__ u16 t[64][68];
  size_t mat = (size_t)blockIdx.z*NELEM;
  const u16* X = Xg + mat; u16* Y = Yg + mat;
  int bx = blockIdx.x*64, by = blockIdx.y*64;
  int c = (threadIdx.x&15)*4, r0 = threadIdx.x>>4;
#pragma unroll
  for(int s=0;s<4;s++){
    int r = r0 + s*16;
    ushort4 v = *(const ushort4*)&X[(size_t)(by+r)*N + bx + c];
    t[r][c]=v.x; t[r][c+1]=v.y; t[r][c+2]=v.z; t[r][c+3]=v.w;
  }
  __syncthreads();
#pragma unroll
  for(int s=0;s<4;s++){
    int r = r0 + s*16;
    ushort4 v;
    v.x=t[c+0][r]; v.y=t[c+1][r]; v.z=t[c+2][r]; v.w=t[c+3][r];
    *(ushort4*)&Y[(size_t)(bx+r)*N + by + c] = v;
  }
}

// NT GEMM: C = alpha*(P*Q^T) + beta*D, optional transposed store to Tg.
// sym=1: blockIdx.x in [0,6) upper-tri tiles, mirror into Tg(=Cg), skip mirror on diag.
// 128x128 tile, 4 waves of 64x64, 16x16x32 bf16 MFMA, global_load_lds staging.
__global__ __launch_bounds__(256)
void k_gemm(const u16* __restrict__ Pg, const u16* __restrict__ Qg,
            u16* __restrict__ Cg, u16* __restrict__ Tg,
            const u16* __restrict__ Dg, float alpha, float beta, int sym){
  __shared__ __align__(16) u16 As[128*32];
  __shared__ __align__(16) u16 Bs[128*32];
  int tid = threadIdx.x, lane = tid&63, w = tid>>6;
  int i0, j0;
  if(sym){
    const int it[6]={0,0,0,1,1,2};
    const int jt[6]={0,1,2,1,2,2};
    i0=it[blockIdx.x]; j0=jt[blockIdx.x];
  } else {
    i0 = blockIdx.x/3; j0 = blockIdx.x - 3*i0;
  }
  size_t mat = (size_t)blockIdx.z*NELEM;
  const u16* P = Pg + mat + (size_t)(i0*128)*N;
  const u16* Q = Qg + mat + (size_t)(j0*128)*N;

  // staging: per wave 2 A-instrs + 2 B-instrs; instr t covers rows (w*2+t)*16..+15
  int srow = lane>>2;           // 0..15
  int scol = (lane&3)*8;        // u16 offset within 32-wide k slice
  const u16* pa0 = P + (size_t)((w*2+0)*16 + srow)*N + scol;
  const u16* pa1 = P + (size_t)((w*2+1)*16 + srow)*N + scol;
  const u16* pb0 = Q + (size_t)((w*2+0)*16 + srow)*N + scol;
  const u16* pb1 = Q + (size_t)((w*2+1)*16 + srow)*N + scol;
  u16* la0 = &As[(w*2+0)*512 + lane*8];
  u16* la1 = &As[(w*2+1)*512 + lane*8];
  u16* lb0 = &Bs[(w*2+0)*512 + lane*8];
  u16* lb1 = &Bs[(w*2+1)*512 + lane*8];

  f32x4 acc[4][4];
#pragma unroll
  for(int r=0;r<4;r++)
#pragma unroll
    for(int c=0;c<4;c++) acc[r][c] = (f32x4)0.f;

  int wm = (w&1)*64, wn = (w>>1)*64;
  int quad = lane>>4, ln = lane&15;

  for(int k0=0;k0<N;k0+=32){
    __syncthreads();
    __builtin_amdgcn_global_load_lds((const __attribute__((address_space(1))) void*)(pa0+k0),
                                     (__attribute__((address_space(3))) void*)la0, 16, 0, 0);
    __builtin_amdgcn_global_load_lds((const __attribute__((address_space(1))) void*)(pa1+k0),
                                     (__attribute__((address_space(3))) void*)la1, 16, 0, 0);
    __builtin_amdgcn_global_load_lds((const __attribute__((address_space(1))) void*)(pb0+k0),
                                     (__attribute__((address_space(3))) void*)lb0, 16, 0, 0);
    __builtin_amdgcn_global_load_lds((const __attribute__((address_space(1))) void*)(pb1+k0),
                                     (__attribute__((address_space(3))) void*)lb1, 16, 0, 0);
    __syncthreads();
    bf16x8 af[4], bv[4];
#pragma unroll
    for(int r=0;r<4;r++) af[r] = *(const bf16x8*)&As[(wm + r*16 + ln)*32 + quad*8];
#pragma unroll
    for(int c=0;c<4;c++) bv[c] = *(const bf16x8*)&Bs[(wn + c*16 + ln)*32 + quad*8];
#pragma unroll
    for(int r=0;r<4;r++)
#pragma unroll
      for(int c=0;c<4;c++)
        acc[r][c] = __builtin_amdgcn_mfma_f32_16x16x32_bf16(af[r], bv[c], acc[r][c], 0, 0, 0);
  }

  // epilogue
  u16* C = Cg + mat;
  const u16* D = Dg ? Dg + mat : nullptr;
  bool do_t = (Tg != nullptr) && !(sym && (i0==j0));
  u16* T = Tg ? Tg + mat : nullptr;
  int rowb = i0*128 + wm, colb = j0*128 + wn;
#pragma unroll
  for(int r=0;r<4;r++){
#pragma unroll
    for(int c=0;c<4;c++){
      int row0 = rowb + r*16 + quad*4;
      int col  = colb + c*16 + ln;
      float v0 = alpha*acc[r][c].x;
      float v1 = alpha*acc[r][c].y;
      float v2 = alpha*acc[r][c].z;
      float v3 = alpha*acc[r][c].w;
      if(D){
        v0 += beta*bf2f(D[(size_t)(row0+0)*N + col]);
        v1 += beta*bf2f(D[(size_t)(row0+1)*N + col]);
        v2 += beta*bf2f(D[(size_t)(row0+2)*N + col]);
        v3 += beta*bf2f(D[(size_t)(row0+3)*N + col]);
      }
      u16 h0=f2bf(v0), h1=f2bf(v1), h2=f2bf(v2), h3=f2bf(v3);
      C[(size_t)(row0+0)*N + col] = h0;
      C[(size_t)(row0+1)*N + col] = h1;
      C[(size_t)(row0+2)*N + col] = h2;
      C[(size_t)(row0+3)*N + col] = h3;
      if(do_t){
        ushort4 pk; pk.x=h0; pk.y=h1; pk.z=h2; pk.w=h3;
        *(ushort4*)&T[(size_t)col*N + row0] = pk;   // T[col][row0..row0+3]
      }
    }
  }
}

// partial trace(X .* (M+eps)): grid (CH,16), atomicAdd into p[m0+mloc]
__global__ __launch_bounds__(256)
void k_trace_part(const u16* __restrict__ Xg, const float* __restrict__ ir,
                  const float* __restrict__ vi, float* __restrict__ p, int m0){
  int mloc = blockIdx.x;
  const float4*  s4 = (const float4*)mat_src(ir, vi, m0+mloc) + blockIdx.y*(NELEM/4/16);
  const ushort4* x4 = (const ushort4*)(Xg + (size_t)mloc*NELEM) + blockIdx.y*(NELEM/4/16);
  float s = 0.f;
  for(int i=threadIdx.x; i<NELEM/4/16; i+=256){
    float4 v = s4[i]; ushort4 x = x4[i];
    s += bf2f(x.x)*(v.x+EPS) + bf2f(x.y)*(v.y+EPS)
       + bf2f(x.z)*(v.z+EPS) + bf2f(x.w)*(v.w+EPS);
  }
  __shared__ float sm[4];
  int lane=threadIdx.x&63, w=threadIdx.x>>6;
  s = wave_sum(s);
  if(lane==0) sm[w]=s;
  __syncthreads();
  if(threadIdx.x==0) atomicAdd(&p[m0+mloc], sm[0]+sm[1]+sm[2]+sm[3]);
}

__global__ void k_weights(const float* __restrict__ p, float* __restrict__ w1, float* __restrict__ w2){
  int c = threadIdx.x;
  if(c < NCH){
    float a = p[c], b = p[c+NCH];
    float den = a + b + EPS;
    w1[c] = a/den;
    w2[c] = b/den;
  }
}

__global__ __launch_bounds__(256)
void k_combine(const float* __restrict__ ir, const float* __restrict__ vi,
               const float* __restrict__ w1, const float* __restrict__ w2,
               float* __restrict__ out){
  int i = blockIdx.x*256 + threadIdx.x;
  int c = i / (NELEM/4);
  float4 a = ((const float4*)ir)[i];
  float4 b = ((const float4*)vi)[i];
  float x1 = w1[c], x2 = w2[c];
  float4 o;
  o.x = x1*a.x + x2*b.x; o.y = x1*a.y + x2*b.y;
  o.z = x1*a.z + x2*b.z; o.w = x1*a.w + x2*b.w;
  ((float4*)out)[i] = o;
}

extern "C" void kernel_launch(void* const* d_in, const int* in_sizes, int n_in,
                              void* d_out, int out_size, void* d_ws, size_t ws_size,
                              hipStream_t stream){
  const float* ir = (const float*)d_in[0];
  const float* vi = (const float*)d_in[1];
  float* out = (float*)d_out;

  // 4 bf16 buffers of CH matrices + small fp32 tail
  int CH = NMAT;
  while(CH > 1 && (size_t)4*CH*NELEM*2 + 4096 > ws_size) CH >>= 1;

  u16* b[4];
  for(int i=0;i<4;i++) b[i] = (u16*)d_ws + (size_t)i*CH*NELEM;
  float* tail = (float*)((u16*)d_ws + (size_t)4*CH*NELEM);
  float* p  = tail;          // NMAT
  float* w1 = p + NMAT;      // NCH
  float* w2 = w1 + NCH;      // NCH
  float* f  = w2 + NCH;      // CH

  k_zero<<<1,256,0,stream>>>(p, NMAT);
  for(int m0=0; m0<NMAT; m0+=CH){
    k_zero<<<1,256,0,stream>>>(f, CH);
    k_frob_part<<<dim3(CH,16),256,0,stream>>>(ir, vi, f, m0);
    k_init<<<dim3(NELEM/4/256,1,CH),256,0,stream>>>(ir, vi, f, b[0], m0);
    k_transp<<<dim3(6,6,CH),256,0,stream>>>(b[0], b[1]);

    int X=0, Y=1, f1=2, f2=3;
    dim3 gs(6,1,CH), gf(9,1,CH);
    // 5 quintic iterations: G=X^T X (via NT(Y,Y)); E=QB*G+QC*G^2; X'=QA*X+X*E; Y'=X'^T
    for(int q=0;q<5;q++){
      k_gemm<<<gs,256,0,stream>>>(b[Y],  b[Y],  b[f1], b[f1], nullptr, 1.f, 0.f, 1);
      k_gemm<<<gs,256,0,stream>>>(b[f1], b[f1], b[f2], b[f2], b[f1],   QC,  QB,  1);
      k_gemm<<<gf,256,0,stream>>>(b[X],  b[f2], b[f1], b[Y],  b[X],    1.f, QA,  0);
      int t=X; X=f1; f1=t;
    }
    // 4 cubic polish: X' = 1.5X - 0.5*X*G
    for(int q=0;q<4;q++){
      k_gemm<<<gs,256,0,stream>>>(b[Y], b[Y],  b[f1], b[f1], nullptr, 1.f,   0.f, 1);
      k_gemm<<<gf,256,0,stream>>>(b[X], b[f1], b[f2], (q==3)?nullptr:b[Y], b[X], -0.5f, 1.5f, 0);
      int t=X; X=f2; f2=t;
    }
    k_trace_part<<<dim3(CH,16),256,0,stream>>>(b[X], ir, vi, p, m0);
  }
  k_weights<<<1,128,0,stream>>>(p, w1, w2);
  k_combine<<<(NCH*(NELEM/4))/256,256,0,stream>>>(ir, vi, w1, w2, out);
}

// Round 3
// 1635.762 us; speedup vs baseline: 6.2661x; 1.5006x over previous
//
#include <hip/hip_runtime.h>
#include <cstddef>

typedef unsigned short u16;
typedef unsigned int u32;

#define N 384
#define NELEM (N*N)        // 147456
#define NCH 128
#define NMAT 256
#define EPS 1e-5f

// Muon quintic coefficients
#define QA 3.4445f
#define QB (-4.7750f)
#define QC 2.0315f

typedef __attribute__((ext_vector_type(8))) short bf16x8;   // 8 bf16 = 4 VGPRs
typedef __attribute__((ext_vector_type(4))) float f32x4;

__device__ __forceinline__ float bf2f(u16 h){ union{u32 u; float f;} v; v.u=((u32)h)<<16; return v.f; }
__device__ __forceinline__ u16 f2bf(float x){
  union{float f;u32 u;} v; v.f=x;
  u32 r=(v.u + 0x7FFFu + ((v.u>>16)&1u))>>16;   // RNE
  return (u16)r;
}

__device__ __forceinline__ float wave_sum(float v){
#pragma unroll
  for(int o=32;o>0;o>>=1) v += __shfl_down(v,o,64);
  return v;
}

__device__ __forceinline__ const float* mat_src(const float* ir, const float* vi, int m){
  return (m < NCH) ? (ir + (size_t)m*NELEM) : (vi + (size_t)(m-NCH)*NELEM);
}

__global__ void k_zero(float* __restrict__ x, int n){
  int i = blockIdx.x*256 + threadIdx.x;
  if(i < n) x[i] = 0.f;
}

// partial Frobenius^2 of (M+eps): grid (CH, 16), atomicAdd into f[mloc]
__global__ __launch_bounds__(256)
void k_frob_part(const float* __restrict__ ir, const float* __restrict__ vi,
                 float* __restrict__ f, int m0){
  int mloc = blockIdx.x;
  const float4* s4 = (const float4*)mat_src(ir, vi, m0+mloc) + blockIdx.y*(NELEM/4/16);
  float s = 0.f;
  for(int i=threadIdx.x; i<NELEM/4/16; i+=256){
    float4 v = s4[i];
    float a=v.x+EPS, b=v.y+EPS, c=v.z+EPS, d=v.w+EPS;
    s += a*a + b*b + c*c + d*d;
  }
  __shared__ float sm[4];
  int lane=threadIdx.x&63, w=threadIdx.x>>6;
  s = wave_sum(s);
  if(lane==0) sm[w]=s;
  __syncthreads();
  if(threadIdx.x==0) atomicAdd(&f[mloc], sm[0]+sm[1]+sm[2]+sm[3]);
}

// X = bf16((M+eps) * rsqrt(f))   grid (144,1,CH)
__global__ __launch_bounds__(256)
void k_init(const float* __restrict__ ir, const float* __restrict__ vi,
            const float* __restrict__ f, u16* __restrict__ Xg, int m0){
  int mloc = blockIdx.z;
  const float4* src = (const float4*)mat_src(ir, vi, m0+mloc);
  float inv = rsqrtf(f[mloc]);
  ushort4* X4 = (ushort4*)(Xg + (size_t)mloc*NELEM);
  int i = blockIdx.x*256 + threadIdx.x;
  float4 v = src[i];
  ushort4 o;
  o.x=f2bf((v.x+EPS)*inv); o.y=f2bf((v.y+EPS)*inv);
  o.z=f2bf((v.z+EPS)*inv); o.w=f2bf((v.w+EPS)*inv);
  X4[i] = o;
}

// Y = X^T (bf16, LDS-tiled)  grid (6,6,CH)
__global__ __launch_bounds__(256)
void k_transp(const u16* __restrict__ Xg, u16* __restrict__ Yg){
  __shared__ u16 t[64][68];
  size_t mat = (size_t)blockIdx.z*NELEM;
  const u16* X = Xg + mat; u16* Y = Yg + mat;
  int bx = blockIdx.x*64, by = blockIdx.y*64;
  int c = (threadIdx.x&15)*4, r0 = threadIdx.x>>4;
#pragma unroll
  for(int s=0;s<4;s++){
    int r = r0 + s*16;
    ushort4 v = *(const ushort4*)&X[(size_t)(by+r)*N + bx + c];
    t[r][c]=v.x; t[r][c+1]=v.y; t[r][c+2]=v.z; t[r][c+3]=v.w;
  }
  __syncthreads();
#pragma unroll
  for(int s=0;s<4;s++){
    int r = r0 + s*16;
    ushort4 v;
    v.x=t[c+0][r]; v.y=t[c+1][r]; v.z=t[c+2][r]; v.w=t[c+3][r];
    *(ushort4*)&Y[(size_t)(bx+r)*N + by + c] = v;
  }
}

// NT GEMM: C = alpha*(P*Q^T) + beta*D, optional transposed store to Tg.
// sym=1: 6 upper-tri tiles/matrix, mirror into Tg(=Cg), skip mirror on diag.
// 1D grid (T*CH blocks), XCD-pinned: matrix m always on XCD m&7.
// LDS uses XOR swizzle: LDS(row, chunk) holds global(row, chunk ^ ((row>>1)&3)),
// realized by swizzling the global SOURCE column in global_load_lds (dest must
// stay base+lane*16). Fragment reads apply the inverse XOR -> 2-way banks (free).
__global__ __launch_bounds__(256)
void k_gemm(const u16* __restrict__ Pg, const u16* __restrict__ Qg,
            u16* __restrict__ Cg, u16* __restrict__ Tg,
            const u16* __restrict__ Dg, float alpha, float beta, int sym){
  __shared__ __align__(16) u16 As[128*32];
  __shared__ __align__(16) u16 Bs[128*32];
  int tid = threadIdx.x, lane = tid&63, w = tid>>6;

  int T = sym ? 6 : 9;
  int CH = gridDim.x / T;
  int m, t;
  if((CH & 7) == 0){
    int xcd = blockIdx.x & 7;
    int b2  = blockIdx.x >> 3;
    t = b2 % T;
    m = xcd + 8*(b2 / T);
  } else {
    m = blockIdx.x / T;
    t = blockIdx.x - m*T;
  }
  int i0, j0;
  if(sym){
    const int it[6]={0,0,0,1,1,2};
    const int jt[6]={0,1,2,1,2,2};
    i0=it[t]; j0=jt[t];
  } else {
    i0 = t/3; j0 = t - 3*i0;
  }
  size_t mat = (size_t)m*NELEM;
  const u16* P = Pg + mat + (size_t)(i0*128)*N;
  const u16* Q = Qg + mat + (size_t)(j0*128)*N;

  // staging: per wave 2 A + 2 B instrs; instr s covers rows (w*2+s)*16..+15.
  // source column swizzled: chunk qs = q0 ^ ((srow>>1)&3)
  int srow = lane>>2;                       // 0..15
  int q0   = lane&3;
  int scol = (q0 ^ ((srow>>1)&3)) * 8;      // u16 offset in 32-wide k slice
  const u16* pa0 = P + (size_t)((w*2+0)*16 + srow)*N + scol;
  const u16* pa1 = P + (size_t)((w*2+1)*16 + srow)*N + scol;
  const u16* pb0 = Q + (size_t)((w*2+0)*16 + srow)*N + scol;
  const u16* pb1 = Q + (size_t)((w*2+1)*16 + srow)*N + scol;
  u16* la0 = &As[(w*2+0)*512 + lane*8];
  u16* la1 = &As[(w*2+1)*512 + lane*8];
  u16* lb0 = &Bs[(w*2+0)*512 + lane*8];
  u16* lb1 = &Bs[(w*2+1)*512 + lane*8];

  f32x4 acc[4][4];
#pragma unroll
  for(int r=0;r<4;r++)
#pragma unroll
    for(int c=0;c<4;c++) acc[r][c] = (f32x4)0.f;

  int wm = (w&1)*64, wn = (w>>1)*64;
  int quad = lane>>4, ln = lane&15;
  // inverse swizzle for fragment reads: chunk = quad ^ ((row>>1)&3); row low bits = ln
  int swz = (quad ^ ((ln>>1)&3)) * 8;

  for(int k0=0;k0<N;k0+=32){
    __syncthreads();
    __builtin_amdgcn_global_load_lds((const __attribute__((address_space(1))) void*)(pa0+k0),
                                     (__attribute__((address_space(3))) void*)la0, 16, 0, 0);
    __builtin_amdgcn_global_load_lds((const __attribute__((address_space(1))) void*)(pa1+k0),
                                     (__attribute__((address_space(3))) void*)la1, 16, 0, 0);
    __builtin_amdgcn_global_load_lds((const __attribute__((address_space(1))) void*)(pb0+k0),
                                     (__attribute__((address_space(3))) void*)lb0, 16, 0, 0);
    __builtin_amdgcn_global_load_lds((const __attribute__((address_space(1))) void*)(pb1+k0),
                                     (__attribute__((address_space(3))) void*)lb1, 16, 0, 0);
    __syncthreads();
    bf16x8 af[4], bv[4];
#pragma unroll
    for(int r=0;r<4;r++) af[r] = *(const bf16x8*)&As[(wm + r*16 + ln)*32 + swz];
#pragma unroll
    for(int c=0;c<4;c++) bv[c] = *(const bf16x8*)&Bs[(wn + c*16 + ln)*32 + swz];
#pragma unroll
    for(int r=0;r<4;r++)
#pragma unroll
      for(int c=0;c<4;c++)
        acc[r][c] = __builtin_amdgcn_mfma_f32_16x16x32_bf16(af[r], bv[c], acc[r][c], 0, 0, 0);
  }

  // epilogue
  u16* C = Cg + mat;
  const u16* D = Dg ? Dg + mat : nullptr;
  bool do_t = (Tg != nullptr) && !(sym && (i0==j0));
  u16* Tm = Tg ? Tg + mat : nullptr;
  int rowb = i0*128 + wm, colb = j0*128 + wn;
#pragma unroll
  for(int r=0;r<4;r++){
#pragma unroll
    for(int c=0;c<4;c++){
      int row0 = rowb + r*16 + quad*4;
      int col  = colb + c*16 + ln;
      float v0 = alpha*acc[r][c].x;
      float v1 = alpha*acc[r][c].y;
      float v2 = alpha*acc[r][c].z;
      float v3 = alpha*acc[r][c].w;
      if(D){
        v0 += beta*bf2f(D[(size_t)(row0+0)*N + col]);
        v1 += beta*bf2f(D[(size_t)(row0+1)*N + col]);
        v2 += beta*bf2f(D[(size_t)(row0+2)*N + col]);
        v3 += beta*bf2f(D[(size_t)(row0+3)*N + col]);
      }
      u16 h0=f2bf(v0), h1=f2bf(v1), h2=f2bf(v2), h3=f2bf(v3);
      C[(size_t)(row0+0)*N + col] = h0;
      C[(size_t)(row0+1)*N + col] = h1;
      C[(size_t)(row0+2)*N + col] = h2;
      C[(size_t)(row0+3)*N + col] = h3;
      if(do_t){
        ushort4 pk; pk.x=h0; pk.y=h1; pk.z=h2; pk.w=h3;
        *(ushort4*)&Tm[(size_t)col*N + row0] = pk;   // T[col][row0..row0+3]
      }
    }
  }
}

// partial trace(X .* (M+eps)): grid (CH,16), atomicAdd into p[m0+mloc]
__global__ __launch_bounds__(256)
void k_trace_part(const u16* __restrict__ Xg, const float* __restrict__ ir,
                  const float* __restrict__ vi, float* __restrict__ p, int m0){
  int mloc = blockIdx.x;
  const float4*  s4 = (const float4*)mat_src(ir, vi, m0+mloc) + blockIdx.y*(NELEM/4/16);
  const ushort4* x4 = (const ushort4*)(Xg + (size_t)mloc*NELEM) + blockIdx.y*(NELEM/4/16);
  float s = 0.f;
  for(int i=threadIdx.x; i<NELEM/4/16; i+=256){
    float4 v = s4[i]; ushort4 x = x4[i];
    s += bf2f(x.x)*(v.x+EPS) + bf2f(x.y)*(v.y+EPS)
       + bf2f(x.z)*(v.z+EPS) + bf2f(x.w)*(v.w+EPS);
  }
  __shared__ float sm[4];
  int lane=threadIdx.x&63, w=threadIdx.x>>6;
  s = wave_sum(s);
  if(lane==0) sm[w]=s;
  __syncthreads();
  if(threadIdx.x==0) atomicAdd(&p[m0+mloc], sm[0]+sm[1]+sm[2]+sm[3]);
}

__global__ void k_weights(const float* __restrict__ p, float* __restrict__ w1, float* __restrict__ w2){
  int c = threadIdx.x;
  if(c < NCH){
    float a = p[c], b = p[c+NCH];
    float den = a + b + EPS;
    w1[c] = a/den;
    w2[c] = b/den;
  }
}

__global__ __launch_bounds__(256)
void k_combine(const float* __restrict__ ir, const float* __restrict__ vi,
               const float* __restrict__ w1, const float* __restrict__ w2,
               float* __restrict__ out){
  int i = blockIdx.x*256 + threadIdx.x;
  int c = i / (NELEM/4);
  float4 a = ((const float4*)ir)[i];
  float4 b = ((const float4*)vi)[i];
  float x1 = w1[c], x2 = w2[c];
  float4 o;
  o.x = x1*a.x + x2*b.x; o.y = x1*a.y + x2*b.y;
  o.z = x1*a.z + x2*b.z; o.w = x1*a.w + x2*b.w;
  ((float4*)out)[i] = o;
}

extern "C" void kernel_launch(void* const* d_in, const int* in_sizes, int n_in,
                              void* d_out, int out_size, void* d_ws, size_t ws_size,
                              hipStream_t stream){
  const float* ir = (const float*)d_in[0];
  const float* vi = (const float*)d_in[1];
  float* out = (float*)d_out;

  // 4 bf16 buffers of CH matrices + small fp32 tail
  int CH = NMAT;
  while(CH > 1 && (size_t)4*CH*NELEM*2 + 4096 > ws_size) CH >>= 1;

  u16* b[4];
  for(int i=0;i<4;i++) b[i] = (u16*)d_ws + (size_t)i*CH*NELEM;
  float* tail = (float*)((u16*)d_ws + (size_t)4*CH*NELEM);
  float* p  = tail;          // NMAT
  float* w1 = p + NMAT;      // NCH
  float* w2 = w1 + NCH;      // NCH
  float* f  = w2 + NCH;      // CH

  k_zero<<<1,256,0,stream>>>(p, NMAT);
  for(int m0=0; m0<NMAT; m0+=CH){
    k_zero<<<1,256,0,stream>>>(f, CH);
    k_frob_part<<<dim3(CH,16),256,0,stream>>>(ir, vi, f, m0);
    k_init<<<dim3(NELEM/4/256,1,CH),256,0,stream>>>(ir, vi, f, b[0], m0);
    k_transp<<<dim3(6,6,CH),256,0,stream>>>(b[0], b[1]);

    int X=0, Y=1, f1=2, f2=3;
    dim3 gs(6*CH), gf(9*CH);
    // 5 quintic iterations: G=X^T X (via NT(Y,Y)); E=QB*G+QC*G^2; X'=QA*X+X*E; Y'=X'^T
    for(int q=0;q<5;q++){
      k_gemm<<<gs,256,0,stream>>>(b[Y],  b[Y],  b[f1], b[f1], nullptr, 1.f, 0.f, 1);
      k_gemm<<<gs,256,0,stream>>>(b[f1], b[f1], b[f2], b[f2], b[f1],   QC,  QB,  1);
      k_gemm<<<gf,256,0,stream>>>(b[X],  b[f2], b[f1], b[Y],  b[X],    1.f, QA,  0);
      int t=X; X=f1; f1=t;
    }
    // 3 cubic polish: X' = 1.5X - 0.5*X*G
    for(int q=0;q<3;q++){
      k_gemm<<<gs,256,0,stream>>>(b[Y], b[Y],  b[f1], b[f1], nullptr, 1.f,   0.f, 1);
      k_gemm<<<gf,256,0,stream>>>(b[X], b[f1], b[f2], (q==2)?nullptr:b[Y], b[X], -0.5f, 1.5f, 0);
      int t=X; X=f2; f2=t;
    }
    k_trace_part<<<dim3(CH,16),256,0,stream>>>(b[X], ir, vi, p, m0);
  }
  k_weights<<<1,128,0,stream>>>(p, w1, w2);
  k_combine<<<(NCH*(NELEM/4))/256,256,0,stream>>>(ir, vi, w1, w2, out);
}